// Round 1
// baseline (1980.302 us; speedup 1.0000x reference)
//
#include <hip/hip_runtime.h>
#include <math.h>

#define D 5
#define B 2048
#define L 50
#define LS 50
#define DH 128
#define DU 128
#define QK 64
#define CD 64
#define EPS 1e-5f

__device__ __forceinline__ float wsum(float v) {
    v += __shfl_xor(v, 1, 64);
    v += __shfl_xor(v, 2, 64);
    v += __shfl_xor(v, 4, 64);
    v += __shfl_xor(v, 8, 64);
    v += __shfl_xor(v, 16, 64);
    v += __shfl_xor(v, 32, 64);
    return v;
}

__device__ __forceinline__ float wmax(float v) {
    v = fmaxf(v, __shfl_xor(v, 1, 64));
    v = fmaxf(v, __shfl_xor(v, 2, 64));
    v = fmaxf(v, __shfl_xor(v, 4, 64));
    v = fmaxf(v, __shfl_xor(v, 8, 64));
    v = fmaxf(v, __shfl_xor(v, 16, 64));
    v = fmaxf(v, __shfl_xor(v, 32, 64));
    return v;
}

// K1: per-b block. Computes h_i[d], h_s[d] for all d, contrastive loss partial,
// and z_sel (selected-domain z) — without ever materializing Ki/Vi/Ks/Vs.
__global__ __launch_bounds__(256) void k1(
    const float* __restrict__ u,
    const float* __restrict__ Hi,   // [D,B,L,DH]
    const float* __restrict__ Hs,   // [B,LS,DH]
    const int* __restrict__ dom_ids,
    const float* __restrict__ Wq, const float* __restrict__ bq,
    const float* __restrict__ Wki,
    const float* __restrict__ Wvi, const float* __restrict__ bvi,
    const float* __restrict__ Wks,
    const float* __restrict__ Wvs, const float* __restrict__ bvs,
    const float* __restrict__ Wf, const float* __restrict__ bf,
    float* __restrict__ z_sel,      // [B,CD]
    float* __restrict__ loss_part)  // [B]
{
    __shared__ float sHs[LS * DH];   // 6400
    __shared__ float sHi[L * DH];    // 6400
    __shared__ float sU[DU];
    __shared__ float sC[DH];
    __shared__ float sQ[QK];
    __shared__ float sqv[DH];        // Wk@Q
    __shared__ float sA[64];         // softmax weights
    __shared__ float sVagg[DH];
    __shared__ float sPart[4 * QK];
    __shared__ float sHid[D * QK];
    __shared__ float sHsd[D * QK];
    __shared__ float sNi[D * QK];
    __shared__ float sNs[D * QK];
    __shared__ float sScore[64];
    __shared__ float sTmp[32];

    const int b = blockIdx.x;
    const int t = threadIdx.x;
    const int lane = t & 63;
    const int wave = t >> 6;

    // stage H_share[b] and u[b]
    {
        const float4* s4 = (const float4*)(Hs + (size_t)b * LS * DH);
        float4* d4 = (float4*)sHs;
        for (int i = t; i < LS * DH / 4; i += 256) d4[i] = s4[i];
    }
    if (t < DU) sU[t] = u[(size_t)b * DU + t];

    for (int d = 0; d < D; ++d) {
        // stage H_intra[d,b]
        {
            const float4* s4 = (const float4*)(Hi + ((size_t)d * B + b) * (L * DH));
            float4* d4 = (float4*)sHi;
            for (int i = t; i < L * DH / 4; i += 256) d4[i] = s4[i];
        }
        __syncthreads();

        // c = mean over L
        if (t < DH) {
            float s = 0.f;
            for (int l = 0; l < L; ++l) s += sHi[l * DH + t];
            sC[t] = s * (1.0f / (float)L);
        }
        __syncthreads();

        // Q = [u, c] @ Wq + bq  (k split across 4 waves)
        {
            float acc = 0.f;
            int k0 = wave * 64;
            if (wave < 2) {
                for (int kk = 0; kk < 64; ++kk) { int k = k0 + kk; acc += sU[k] * Wq[k * QK + lane]; }
            } else {
                for (int kk = 0; kk < 64; ++kk) { int k = k0 + kk; acc += sC[k - DU] * Wq[k * QK + lane]; }
            }
            sPart[wave * QK + lane] = acc;
        }
        __syncthreads();
        if (t < QK) sQ[t] = bq[t] + sPart[t] + sPart[QK + t] + sPart[2 * QK + t] + sPart[3 * QK + t];
        __syncthreads();

        float qreg = sQ[lane];

        // ---------- intra attention ----------
        // qi = Wki @ Q  (wave-row, coalesced weight reads, shuffle reduce)
        for (int k = wave; k < DH; k += 4) {
            float v = Wki[k * QK + lane] * qreg;
            v = wsum(v);
            if (lane == 0) sqv[k] = v;
        }
        __syncthreads();
        // scores_l = (H_l . qi) / 8   (bki dropped: softmax shift-invariant)
        for (int l = wave; l < L; l += 4) {
            float v = sHi[l * DH + lane] * sqv[lane] + sHi[l * DH + 64 + lane] * sqv[64 + lane];
            v = wsum(v);
            if (lane == 0) sScore[l] = v * 0.125f;
        }
        __syncthreads();
        if (wave == 0) {
            float s = (lane < L) ? sScore[lane] : -3.0e38f;
            float m = wmax(s);
            float e = (lane < L) ? expf(s - m) : 0.f;
            float ssum = wsum(e);
            if (lane < L) sA[lane] = e / ssum;
        }
        __syncthreads();
        // v_agg = sum_l a_l H_l
        if (t < DH) {
            float acc = 0.f;
            for (int l = 0; l < L; ++l) acc += sA[l] * sHi[l * DH + t];
            sVagg[t] = acc;
        }
        __syncthreads();
        // h_i = v_agg @ Wvi + bvi
        {
            float acc = 0.f;
            int kb = wave * 32;
            for (int kk = 0; kk < 32; ++kk) { int k = kb + kk; acc += sVagg[k] * Wvi[k * QK + lane]; }
            sPart[wave * QK + lane] = acc;
        }
        __syncthreads();
        if (t < QK) sHid[d * QK + t] = bvi[t] + sPart[t] + sPart[QK + t] + sPart[2 * QK + t] + sPart[3 * QK + t];
        __syncthreads();

        // ---------- shared attention ----------
        for (int k = wave; k < DH; k += 4) {
            float v = Wks[k * QK + lane] * qreg;
            v = wsum(v);
            if (lane == 0) sqv[k] = v;
        }
        __syncthreads();
        for (int l = wave; l < LS; l += 4) {
            float v = sHs[l * DH + lane] * sqv[lane] + sHs[l * DH + 64 + lane] * sqv[64 + lane];
            v = wsum(v);
            if (lane == 0) sScore[l] = v * 0.125f;
        }
        __syncthreads();
        if (wave == 0) {
            float s = (lane < LS) ? sScore[lane] : -3.0e38f;
            float m = wmax(s);
            float e = (lane < LS) ? expf(s - m) : 0.f;
            float ssum = wsum(e);
            if (lane < LS) sA[lane] = e / ssum;
        }
        __syncthreads();
        if (t < DH) {
            float acc = 0.f;
            for (int l = 0; l < LS; ++l) acc += sA[l] * sHs[l * DH + t];
            sVagg[t] = acc;
        }
        __syncthreads();
        {
            float acc = 0.f;
            int kb = wave * 32;
            for (int kk = 0; kk < 32; ++kk) { int k = kb + kk; acc += sVagg[k] * Wvs[k * QK + lane]; }
            sPart[wave * QK + lane] = acc;
        }
        __syncthreads();
        if (t < QK) sHsd[d * QK + t] = bvs[t] + sPart[t] + sPart[QK + t] + sPart[2 * QK + t] + sPart[3 * QK + t];
        __syncthreads();
    }

    // ---------- contrastive loss partial ----------
    for (int v = wave; v < 2 * D; v += 4) {
        const float* vec = (v < D) ? (sHid + v * QK) : (sHsd + (v - D) * QK);
        float x = vec[lane];
        float ss = wsum(x * x);
        if (lane == 0) sTmp[v] = 1.0f / fmaxf(sqrtf(ss), 1e-12f);
    }
    __syncthreads();
    for (int i = t; i < D * QK; i += 256) {
        int dd = i / QK;
        sNi[i] = sHid[i] * sTmp[dd];
        sNs[i] = sHsd[i] * sTmp[D + dd];
    }
    __syncthreads();
    if (t < D * D) {
        int dd = t / D, e = t % D;
        float s = 0.f;
        for (int n = 0; n < QK; ++n) s += sNi[dd * QK + n] * sNi[e * QK + n];
        sScore[t] = expf(s);
    }
    __syncthreads();
    if (t < D) {
        float pos = 0.f;
        for (int n = 0; n < QK; ++n) pos += sNi[t * QK + n] * sNs[t * QK + n];
        float denom = 0.f;
        for (int e = 0; e < D; ++e) denom += sScore[t * D + e];
        sTmp[16 + t] = logf(expf(pos) / (denom + 1e-8f) + 1e-8f);
    }
    __syncthreads();
    if (t == 0) {
        float s = 0.f;
        for (int dd = 0; dd < D; ++dd) s += sTmp[16 + dd];
        loss_part[b] = s;
    }

    // ---------- z for selected domain only ----------
    int dm = dom_ids[b];
    if (t < CD) {
        float acc = bf[t];
        for (int k = 0; k < QK; ++k) acc += sHid[dm * QK + k] * Wf[k * CD + t];
        for (int k = 0; k < QK; ++k) acc += sHsd[dm * QK + k] * Wf[(QK + k) * CD + t];
        z_sel[(size_t)b * CD + t] = acc;
    }
}

// K2: segment mean/var per (domain, dim). One block per dim.
__global__ __launch_bounds__(256) void k2(
    const float* __restrict__ h, const int* __restrict__ dom_ids,
    float* __restrict__ mean_d, float* __restrict__ var_d)
{
    __shared__ float sSum[D], sSq[D], sCnt[D];
    const int j = blockIdx.x;
    const int t = threadIdx.x;
    const int lane = t & 63;
    if (t < D) { sSum[t] = 0.f; sSq[t] = 0.f; sCnt[t] = 0.f; }
    __syncthreads();

    float a0 = 0, a1 = 0, a2 = 0, a3 = 0, a4 = 0;
    float q0 = 0, q1 = 0, q2 = 0, q3 = 0, q4 = 0;
    float c0 = 0, c1 = 0, c2 = 0, c3 = 0, c4 = 0;
    for (int b = t; b < B; b += 256) {
        float v = h[(size_t)b * DH + j];
        int dm = dom_ids[b];
        float v2 = v * v;
        if (dm == 0) { a0 += v; q0 += v2; c0 += 1.f; }
        else if (dm == 1) { a1 += v; q1 += v2; c1 += 1.f; }
        else if (dm == 2) { a2 += v; q2 += v2; c2 += 1.f; }
        else if (dm == 3) { a3 += v; q3 += v2; c3 += 1.f; }
        else { a4 += v; q4 += v2; c4 += 1.f; }
    }
    a0 = wsum(a0); a1 = wsum(a1); a2 = wsum(a2); a3 = wsum(a3); a4 = wsum(a4);
    q0 = wsum(q0); q1 = wsum(q1); q2 = wsum(q2); q3 = wsum(q3); q4 = wsum(q4);
    c0 = wsum(c0); c1 = wsum(c1); c2 = wsum(c2); c3 = wsum(c3); c4 = wsum(c4);
    if (lane == 0) {
        atomicAdd(&sSum[0], a0); atomicAdd(&sSum[1], a1); atomicAdd(&sSum[2], a2);
        atomicAdd(&sSum[3], a3); atomicAdd(&sSum[4], a4);
        atomicAdd(&sSq[0], q0); atomicAdd(&sSq[1], q1); atomicAdd(&sSq[2], q2);
        atomicAdd(&sSq[3], q3); atomicAdd(&sSq[4], q4);
        atomicAdd(&sCnt[0], c0); atomicAdd(&sCnt[1], c1); atomicAdd(&sCnt[2], c2);
        atomicAdd(&sCnt[3], c3); atomicAdd(&sCnt[4], c4);
    }
    __syncthreads();
    if (t < D) {
        float c = fmaxf(sCnt[t], 1.0f);
        float m = sSum[t] / c;
        mean_d[t * DH + j] = m;
        var_d[t * DH + j] = sSq[t] / c - m * m;
    }
}

// K3: gb = z_sel @ Wgb + bgb; out = gamma*h_norm + beta + h. One block per b.
__global__ __launch_bounds__(256) void k3(
    const float* __restrict__ h, const int* __restrict__ dom_ids,
    const float* __restrict__ Wgb, const float* __restrict__ bgb,
    const float* __restrict__ z_sel,
    const float* __restrict__ mean_d, const float* __restrict__ var_d,
    float* __restrict__ out)
{
    __shared__ float sZ[CD];
    __shared__ float sGB[2 * DH];
    const int b = blockIdx.x;
    const int t = threadIdx.x;
    if (t < CD) sZ[t] = z_sel[(size_t)b * CD + t];
    __syncthreads();
    float acc = bgb[t];
    for (int k = 0; k < CD; ++k) acc += sZ[k] * Wgb[k * (2 * DH) + t];
    sGB[t] = acc;
    __syncthreads();
    if (t < DH) {
        int dm = dom_ids[b];
        float hv = h[(size_t)b * DH + t];
        float mu = mean_d[dm * DH + t];
        float va = var_d[dm * DH + t];
        float hn = (hv - mu) / sqrtf(va + EPS);
        out[(size_t)b * DH + t] = sGB[t] * hn + sGB[DH + t] + hv;
    }
}

// K4: reduce loss partials -> scalar at d_out[B*DH]
__global__ __launch_bounds__(256) void k4(const float* __restrict__ loss_part,
                                          float* __restrict__ out_scalar)
{
    __shared__ float red[4];
    const int t = threadIdx.x;
    float s = 0.f;
    for (int i = t; i < B; i += 256) s += loss_part[i];
    s = wsum(s);
    if ((t & 63) == 0) red[t >> 6] = s;
    __syncthreads();
    if (t == 0) out_scalar[0] = -(red[0] + red[1] + red[2] + red[3]) / (float)(B * D);
}

extern "C" void kernel_launch(void* const* d_in, const int* in_sizes, int n_in,
                              void* d_out, int out_size, void* d_ws, size_t ws_size,
                              hipStream_t stream)
{
    (void)in_sizes; (void)n_in; (void)out_size; (void)ws_size;
    const float* u   = (const float*)d_in[0];
    const float* Hi  = (const float*)d_in[1];
    const float* Hs  = (const float*)d_in[2];
    const float* h   = (const float*)d_in[3];
    const int*   dom = (const int*)d_in[4];
    const float* Wq  = (const float*)d_in[5];
    const float* bq  = (const float*)d_in[6];
    const float* Wki = (const float*)d_in[7];
    // d_in[8] = bki: unused (softmax shift-invariance)
    const float* Wvi = (const float*)d_in[9];
    const float* bvi = (const float*)d_in[10];
    const float* Wks = (const float*)d_in[11];
    // d_in[12] = bks: unused (softmax shift-invariance)
    const float* Wvs = (const float*)d_in[13];
    const float* bvs = (const float*)d_in[14];
    const float* Wf  = (const float*)d_in[15];
    const float* bf  = (const float*)d_in[16];
    const float* Wgb = (const float*)d_in[17];
    const float* bgb = (const float*)d_in[18];

    float* out = (float*)d_out;
    float* ws = (float*)d_ws;
    float* z_sel     = ws;                  // B*CD
    float* loss_part = z_sel + (size_t)B * CD; // B
    float* mean_d    = loss_part + B;       // D*DH
    float* var_d     = mean_d + D * DH;     // D*DH

    hipLaunchKernelGGL(k1, dim3(B), dim3(256), 0, stream,
                       u, Hi, Hs, dom, Wq, bq, Wki, Wvi, bvi, Wks, Wvs, bvs, Wf, bf,
                       z_sel, loss_part);
    hipLaunchKernelGGL(k2, dim3(DH), dim3(256), 0, stream, h, dom, mean_d, var_d);
    hipLaunchKernelGGL(k3, dim3(B), dim3(256), 0, stream,
                       h, dom, Wgb, bgb, z_sel, mean_d, var_d, out);
    hipLaunchKernelGGL(k4, dim3(1), dim3(256), 0, stream, loss_part, out + (size_t)B * DH);
}

// Round 2
// 716.548 us; speedup vs baseline: 2.7637x; 2.7637x over previous
//
#include <hip/hip_runtime.h>
#include <math.h>

#define D 5
#define B 2048
#define L 50
#define LS 50
#define DH 128
#define DU 128
#define QK 64
#define CD 64
#define EPS 1e-5f

__device__ __forceinline__ float wsum(float v) {
    v += __shfl_xor(v, 1, 64);
    v += __shfl_xor(v, 2, 64);
    v += __shfl_xor(v, 4, 64);
    v += __shfl_xor(v, 8, 64);
    v += __shfl_xor(v, 16, 64);
    v += __shfl_xor(v, 32, 64);
    return v;
}

__device__ __forceinline__ float wmax(float v) {
    v = fmaxf(v, __shfl_xor(v, 1, 64));
    v = fmaxf(v, __shfl_xor(v, 2, 64));
    v = fmaxf(v, __shfl_xor(v, 4, 64));
    v = fmaxf(v, __shfl_xor(v, 8, 64));
    v = fmaxf(v, __shfl_xor(v, 16, 64));
    v = fmaxf(v, __shfl_xor(v, 32, 64));
    return v;
}

// kin: one block per (d,b). Stages H_intra[d,b] once, computes c, Q, qvi, qvs,
// intra attention, h_i. Writes qvs (for ksh) and h_i (for kfin).
__global__ __launch_bounds__(256) void kin(
    const float* __restrict__ u,
    const float* __restrict__ Hi,   // [D,B,L,DH]
    const float* __restrict__ Wq, const float* __restrict__ bq,
    const float* __restrict__ Wki,
    const float* __restrict__ Wvi, const float* __restrict__ bvi,
    const float* __restrict__ Wks,
    float* __restrict__ qvs_w,      // [D,B,DH]
    float* __restrict__ hi_w)       // [D,B,QK]
{
    __shared__ float sHi[L * DH];   // 6400
    __shared__ float sU[DU];
    __shared__ float sC[DH];
    __shared__ float sQ[QK];
    __shared__ float sPart[4 * QK];
    __shared__ float sPC[256];
    __shared__ float sQVi[DH];
    __shared__ float sSc[64];
    __shared__ float sA[64];

    const int b = blockIdx.x;
    const int d = blockIdx.y;
    const int t = threadIdx.x;
    const int lane = t & 63;
    const int wave = t >> 6;

    // stage H_intra[d,b] (float4 coalesced) + u[b]
    {
        const float4* s4 = (const float4*)(Hi + ((size_t)d * B + b) * (L * DH));
        float4* d4 = (float4*)sHi;
        for (int i = t; i < L * DH / 4; i += 256) d4[i] = s4[i];
    }
    if (t < DU) sU[t] = u[(size_t)b * DU + t];
    __syncthreads();

    // c = mean over L (split L across two halves of the block)
    {
        const int col = t & 127, half = t >> 7;
        float s = 0.f;
        const int l0 = half * 25;
        for (int l = l0; l < l0 + 25; ++l) s += sHi[l * DH + col];
        sPC[t] = s;
    }
    __syncthreads();
    if (t < DH) sC[t] = (sPC[t] + sPC[t + 128]) * (1.0f / (float)L);
    __syncthreads();

    // Q = [u, c] @ Wq + bq  (split-k across 4 waves; Wq reads coalesced)
    {
        float acc = 0.f;
        const int k0 = wave * 64;
        if (wave < 2) {
            for (int kk = 0; kk < 64; ++kk) { int k = k0 + kk; acc += sU[k] * Wq[k * QK + lane]; }
        } else {
            for (int kk = 0; kk < 64; ++kk) { int k = k0 + kk; acc += sC[k - DU] * Wq[k * QK + lane]; }
        }
        sPart[wave * QK + lane] = acc;
    }
    __syncthreads();
    if (t < QK) sQ[t] = bq[t] + sPart[t] + sPart[QK + t] + sPart[2 * QK + t] + sPart[3 * QK + t];
    __syncthreads();

    // qvi = Wki@Q (threads 0..127), qvs = Wks@Q (threads 128..255); vectorized rows
    {
        const int k = t & 127;
        const float4* W4 = (t < 128) ? (const float4*)(Wki + k * QK)
                                     : (const float4*)(Wks + k * QK);
        float acc = 0.f;
        for (int q4 = 0; q4 < 16; ++q4) {
            float4 w = W4[q4];
            acc += w.x * sQ[q4 * 4] + w.y * sQ[q4 * 4 + 1]
                 + w.z * sQ[q4 * 4 + 2] + w.w * sQ[q4 * 4 + 3];
        }
        if (t < 128) sQVi[k] = acc;
        else qvs_w[((size_t)d * B + b) * DH + k] = acc;  // direct global write
    }
    __syncthreads();

    // scores_l = (H_l . qvi)/8  (bias dropped: softmax shift-invariant)
    for (int l = wave; l < L; l += 4) {
        float v = sHi[l * DH + lane] * sQVi[lane] + sHi[l * DH + 64 + lane] * sQVi[64 + lane];
        v = wsum(v);
        if (lane == 0) sSc[l] = v * 0.125f;
    }
    __syncthreads();
    if (wave == 0) {
        float s = (lane < L) ? sSc[lane] : -3.0e38f;
        float m = wmax(s);
        float e = (lane < L) ? expf(s - m) : 0.f;
        float ssum = wsum(e);
        if (lane < L) sA[lane] = e / ssum;
    }
    __syncthreads();

    // v_agg partials (L split across halves)
    {
        const int col = t & 127, half = t >> 7;
        float acc = 0.f;
        const int l0 = half * 25;
        for (int l = l0; l < l0 + 25; ++l) acc += sA[l] * sHi[l * DH + col];
        sPC[t] = acc;
    }
    __syncthreads();

    // h_i = v_agg @ Wvi + bvi (split-k 4 waves, combine v_agg halves inline)
    {
        float acc = 0.f;
        const int k0 = wave * 32;
        for (int kk = 0; kk < 32; ++kk) {
            int k = k0 + kk;
            acc += (sPC[k] + sPC[128 + k]) * Wvi[k * QK + lane];
        }
        sPart[wave * QK + lane] = acc;
    }
    __syncthreads();
    if (t < QK) {
        hi_w[((size_t)d * B + b) * QK + t] =
            bvi[t] + sPart[t] + sPart[QK + t] + sPart[2 * QK + t] + sPart[3 * QK + t];
    }
}

// ksh: one block per b. Shared attention for all 5 domains in parallel.
__global__ __launch_bounds__(256) void ksh(
    const float* __restrict__ Hs,     // [B,LS,DH]
    const float* __restrict__ qvs_w,  // [D,B,DH]
    const float* __restrict__ Wvs, const float* __restrict__ bvs,
    float* __restrict__ hs_w)         // [D,B,QK]
{
    __shared__ float sHs[LS * DH];   // 6400
    __shared__ float sQV[D * DH];    // 640
    __shared__ float sS[D * 64];     // scores -> softmax weights
    __shared__ float sV[D * DH];     // v_agg

    const int b = blockIdx.x;
    const int t = threadIdx.x;
    const int lane = t & 63;
    const int wave = t >> 6;

    {
        const float4* s4 = (const float4*)(Hs + (size_t)b * LS * DH);
        float4* d4 = (float4*)sHs;
        for (int i = t; i < LS * DH / 4; i += 256) d4[i] = s4[i];
    }
    for (int i = t; i < D * DH; i += 256) {
        int dd = i >> 7, k = i & 127;
        sQV[i] = qvs_w[((size_t)dd * B + b) * DH + k];
    }
    __syncthreads();

    // 250 score rows over 4 waves
    for (int r = wave; r < D * LS; r += 4) {
        int dd = r / LS, l = r - dd * LS;
        float v = sHs[l * DH + lane] * sQV[dd * DH + lane]
                + sHs[l * DH + 64 + lane] * sQV[dd * DH + 64 + lane];
        v = wsum(v);
        if (lane == 0) sS[dd * 64 + l] = v * 0.125f;
    }
    __syncthreads();

    // 5 softmaxes, waves in parallel
    for (int dd = wave; dd < D; dd += 4) {
        float s = (lane < LS) ? sS[dd * 64 + lane] : -3.0e38f;
        float m = wmax(s);
        float e = (lane < LS) ? expf(s - m) : 0.f;
        float ssum = wsum(e);
        if (lane < LS) sS[dd * 64 + lane] = e / ssum;
    }
    __syncthreads();

    // v_agg for all d: 640 outputs
    for (int o = t; o < D * DH; o += 256) {
        int dd = o >> 7, col = o & 127;
        float acc = 0.f;
        for (int l = 0; l < LS; ++l) acc += sS[dd * 64 + l] * sHs[l * DH + col];
        sV[o] = acc;
    }
    __syncthreads();

    // h_s = v_agg @ Wvs + bvs: 320 outputs
    for (int o = t; o < D * QK; o += 256) {
        int dd = o >> 6, q = o & 63;
        float acc = bvs[q];
        for (int k = 0; k < DH; ++k) acc += sV[dd * DH + k] * Wvs[k * QK + q];
        hs_w[((size_t)dd * B + b) * QK + q] = acc;
    }
}

// kstat: segment sums of h per (domain, dim), coalesced. 64 blocks x 32 rows.
__global__ __launch_bounds__(256) void kstat(
    const float* __restrict__ h, const int* __restrict__ dom_ids,
    float* __restrict__ gsum, float* __restrict__ gsq, float* __restrict__ gcnt)
{
    __shared__ float sS[D * DH], sQ2[D * DH], sCnt[D];
    const int t = threadIdx.x;
    const int b0 = blockIdx.x * 32;
    for (int i = t; i < D * DH; i += 256) { sS[i] = 0.f; sQ2[i] = 0.f; }
    if (t < D) sCnt[t] = 0.f;
    __syncthreads();
    const int col = t & 127, half = t >> 7;
    for (int rr = 0; rr < 16; ++rr) {
        int b = b0 + rr * 2 + half;
        float v = h[(size_t)b * DH + col];
        int dm = dom_ids[b];
        atomicAdd(&sS[dm * DH + col], v);
        atomicAdd(&sQ2[dm * DH + col], v * v);
        if (col == 0) atomicAdd(&sCnt[dm], 1.f);
    }
    __syncthreads();
    for (int i = t; i < D * DH; i += 256) {
        atomicAdd(&gsum[i], sS[i]);
        atomicAdd(&gsq[i], sQ2[i]);
    }
    if (t < D) atomicAdd(&gcnt[t], sCnt[t]);
}

__global__ __launch_bounds__(256) void kstat2(
    const float* __restrict__ gsum, const float* __restrict__ gsq,
    const float* __restrict__ gcnt,
    float* __restrict__ mean_d, float* __restrict__ var_d)
{
    const int t = threadIdx.x;
    for (int i = t; i < D * DH; i += 256) {
        int dd = i >> 7;
        float c = fmaxf(gcnt[dd], 1.0f);
        float m = gsum[i] / c;
        mean_d[i] = m;
        var_d[i] = gsq[i] / c - m * m;
    }
}

// kfin: one block per b. Loss partial (atomicAdd), z_sel, gb, AdaNorm epilogue.
__global__ __launch_bounds__(256) void kfin(
    const float* __restrict__ h, const int* __restrict__ dom_ids,
    const float* __restrict__ hi_w, const float* __restrict__ hs_w,
    const float* __restrict__ Wf, const float* __restrict__ bf,
    const float* __restrict__ Wgb, const float* __restrict__ bgb,
    const float* __restrict__ mean_d, const float* __restrict__ var_d,
    float* __restrict__ out, float* __restrict__ loss_out)
{
    __shared__ float sHi[D * QK], sHs[D * QK], sNi[D * QK], sNs[D * QK];
    __shared__ float sInv[16], sE[32], sPos[8], sLg[8], sZ[QK], sGB[2 * DH];

    const int b = blockIdx.x;
    const int t = threadIdx.x;
    const int lane = t & 63;
    const int wave = t >> 6;

    for (int i = t; i < D * QK; i += 256) {
        int dd = i >> 6, q = i & 63;
        sHi[i] = hi_w[((size_t)dd * B + b) * QK + q];
        sHs[i] = hs_w[((size_t)dd * B + b) * QK + q];
    }
    __syncthreads();

    for (int v = wave; v < 2 * D; v += 4) {
        float x = (v < D) ? sHi[v * QK + lane] : sHs[(v - D) * QK + lane];
        float ss = wsum(x * x);
        if (lane == 0) sInv[v] = 1.0f / fmaxf(sqrtf(ss), 1e-12f);
    }
    __syncthreads();
    for (int i = t; i < D * QK; i += 256) {
        int dd = i >> 6;
        sNi[i] = sHi[i] * sInv[dd];
        sNs[i] = sHs[i] * sInv[D + dd];
    }
    __syncthreads();
    if (t < D * D) {
        int dd = t / D, e = t - dd * D;
        float s = 0.f;
        for (int n = 0; n < QK; ++n) s += sNi[dd * QK + n] * sNi[e * QK + n];
        sE[t] = expf(s);
    }
    if (t >= 64 && t < 64 + D) {
        int dd = t - 64;
        float s = 0.f;
        for (int n = 0; n < QK; ++n) s += sNi[dd * QK + n] * sNs[dd * QK + n];
        sPos[dd] = s;
    }
    __syncthreads();
    if (t < D) {
        float den = 0.f;
        for (int e = 0; e < D; ++e) den += sE[t * D + e];
        sLg[t] = logf(expf(sPos[t]) / (den + 1e-8f) + 1e-8f);
    }
    __syncthreads();

    const int dm = dom_ids[b];
    if (t == 0) {
        float s = sLg[0] + sLg[1] + sLg[2] + sLg[3] + sLg[4];
        atomicAdd(loss_out, -s / (float)(B * D));
    }
    if (t < QK) {
        float acc = bf[t];
        for (int k = 0; k < QK; ++k) acc += sHi[dm * QK + k] * Wf[k * CD + t];
        for (int k = 0; k < QK; ++k) acc += sHs[dm * QK + k] * Wf[(QK + k) * CD + t];
        sZ[t] = acc;
    }
    __syncthreads();
    {
        float acc = bgb[t];
        for (int k = 0; k < CD; ++k) acc += sZ[k] * Wgb[k * (2 * DH) + t];
        sGB[t] = acc;
    }
    __syncthreads();
    if (t < DH) {
        float hv = h[(size_t)b * DH + t];
        float mu = mean_d[dm * DH + t];
        float va = var_d[dm * DH + t];
        float hn = (hv - mu) / sqrtf(va + EPS);
        out[(size_t)b * DH + t] = sGB[t] * hn + sGB[DH + t] + hv;
    }
}

extern "C" void kernel_launch(void* const* d_in, const int* in_sizes, int n_in,
                              void* d_out, int out_size, void* d_ws, size_t ws_size,
                              hipStream_t stream)
{
    (void)in_sizes; (void)n_in; (void)out_size; (void)ws_size;
    const float* u   = (const float*)d_in[0];
    const float* Hi  = (const float*)d_in[1];
    const float* Hs  = (const float*)d_in[2];
    const float* h   = (const float*)d_in[3];
    const int*   dom = (const int*)d_in[4];
    const float* Wq  = (const float*)d_in[5];
    const float* bq  = (const float*)d_in[6];
    const float* Wki = (const float*)d_in[7];
    // d_in[8] = bki: unused (softmax shift-invariance)
    const float* Wvi = (const float*)d_in[9];
    const float* bvi = (const float*)d_in[10];
    const float* Wks = (const float*)d_in[11];
    // d_in[12] = bks: unused (softmax shift-invariance)
    const float* Wvs = (const float*)d_in[13];
    const float* bvs = (const float*)d_in[14];
    const float* Wf  = (const float*)d_in[15];
    const float* bf  = (const float*)d_in[16];
    const float* Wgb = (const float*)d_in[17];
    const float* bgb = (const float*)d_in[18];

    float* out = (float*)d_out;
    float* loss_out = out + (size_t)B * DH;

    float* ws = (float*)d_ws;
    float* qvs_w  = ws;                               // D*B*DH
    float* hi_w   = qvs_w + (size_t)D * B * DH;       // D*B*QK
    float* hs_w   = hi_w + (size_t)D * B * QK;        // D*B*QK
    float* gsum   = hs_w + (size_t)D * B * QK;        // D*DH
    float* gsq    = gsum + D * DH;                    // D*DH
    float* gcnt   = gsq + D * DH;                     // 8
    float* mean_d = gcnt + 8;                         // D*DH
    float* var_d  = mean_d + D * DH;                  // D*DH

    // zero the accumulators (graph-capturable async memsets)
    hipMemsetAsync(gsum, 0, (size_t)(2 * D * DH + 8) * sizeof(float), stream);
    hipMemsetAsync(loss_out, 0, sizeof(float), stream);

    hipLaunchKernelGGL(kstat, dim3(B / 32), dim3(256), 0, stream, h, dom, gsum, gsq, gcnt);
    hipLaunchKernelGGL(kstat2, dim3(1), dim3(256), 0, stream, gsum, gsq, gcnt, mean_d, var_d);
    hipLaunchKernelGGL(kin, dim3(B, D), dim3(256), 0, stream,
                       u, Hi, Wq, bq, Wki, Wvi, bvi, Wks, qvs_w, hi_w);
    hipLaunchKernelGGL(ksh, dim3(B), dim3(256), 0, stream, Hs, qvs_w, Wvs, bvs, hs_w);
    hipLaunchKernelGGL(kfin, dim3(B), dim3(256), 0, stream,
                       h, dom, hi_w, hs_w, Wf, bf, Wgb, bgb, mean_d, var_d, out, loss_out);
}

// Round 3
// 612.745 us; speedup vs baseline: 3.2319x; 1.1694x over previous
//
#include <hip/hip_runtime.h>
#include <math.h>

#define D 5
#define B 2048
#define L 50
#define LS 50
#define DH 128
#define DU 128
#define QK 64
#define CD 64
#define EPS 1e-5f

__device__ __forceinline__ float wsum(float v) {
    v += __shfl_xor(v, 1, 64);
    v += __shfl_xor(v, 2, 64);
    v += __shfl_xor(v, 4, 64);
    v += __shfl_xor(v, 8, 64);
    v += __shfl_xor(v, 16, 64);
    v += __shfl_xor(v, 32, 64);
    return v;
}

__device__ __forceinline__ float wmax(float v) {
    v = fmaxf(v, __shfl_xor(v, 1, 64));
    v = fmaxf(v, __shfl_xor(v, 2, 64));
    v = fmaxf(v, __shfl_xor(v, 4, 64));
    v = fmaxf(v, __shfl_xor(v, 8, 64));
    v = fmaxf(v, __shfl_xor(v, 16, 64));
    v = fmaxf(v, __shfl_xor(v, 32, 64));
    return v;
}

// reduction across a 32-lane group (xor bits 0..4 keep t>>5 invariant)
__device__ __forceinline__ float gsum32(float v) {
    v += __shfl_xor(v, 1, 64);
    v += __shfl_xor(v, 2, 64);
    v += __shfl_xor(v, 4, 64);
    v += __shfl_xor(v, 8, 64);
    v += __shfl_xor(v, 16, 64);
    return v;
}

__device__ __forceinline__ float dot4(float4 a, float4 b) {
    return a.x * b.x + a.y * b.y + a.z * b.z + a.w * b.w;
}

// kin: one block per (b,d). H_intra tile register-resident.
// Thread layout: g = t>>5 (row group), col4 = t&31 (float4 column);
// thread owns rows r = g + 8k (k < nrow), cols 4*col4 .. 4*col4+3.
__global__ __launch_bounds__(256, 6) void kin(
    const float* __restrict__ u,
    const float* __restrict__ Hi,   // [D,B,L,DH]
    const float* __restrict__ Wq, const float* __restrict__ bq,
    const float* __restrict__ Wki,
    const float* __restrict__ Wvi, const float* __restrict__ bvi,
    const float* __restrict__ Wks,
    float* __restrict__ qvs_w,      // [D,B,DH]
    float* __restrict__ hi_w)       // [D,B,QK]
{
    __shared__ float4 sP4[256];      // 4 KB: csum partials, then vagg partials
    __shared__ float sC[DH];
    __shared__ float sPart[4 * QK];
    __shared__ float sQ[QK];
    __shared__ float sQVi[DH];
    __shared__ float sSc[64];
    __shared__ float sA[64];
    __shared__ float sVagg[DH];

    const int b = blockIdx.x, d = blockIdx.y;
    const int t = threadIdx.x;
    const int lane = t & 63;
    const int wave = t >> 6;
    const int g = t >> 5;
    const int col4 = t & 31;
    const int nrow = (g < 2) ? 7 : 6;
    const float* sPf = (const float*)sP4;

    // load H tile into registers (coalesced b128: 1 KB per wave instr)
    const float* Hbase = Hi + ((size_t)d * B + b) * (L * DH);
    float4 h4[7];
    #pragma unroll
    for (int k = 0; k < 7; ++k) {
        if (k < nrow) h4[k] = *(const float4*)(Hbase + (g + 8 * k) * DH + 4 * col4);
    }

    // c partials
    {
        float4 cs = make_float4(0.f, 0.f, 0.f, 0.f);
        #pragma unroll
        for (int k = 0; k < 7; ++k) {
            if (k < nrow) { cs.x += h4[k].x; cs.y += h4[k].y; cs.z += h4[k].z; cs.w += h4[k].w; }
        }
        sP4[t] = cs;
    }
    __syncthreads();
    if (t < DH) {
        float s = 0.f;
        #pragma unroll
        for (int gg = 0; gg < 8; ++gg) s += sPf[gg * 128 + t];
        sC[t] = s * (1.0f / (float)L);
    }
    __syncthreads();

    // Q = [u, c] @ Wq + bq, split-k 4x48
    {
        float acc = 0.f;
        const int k0 = wave * 48;
        #pragma unroll 8
        for (int i = 0; i < 48; ++i) {
            int k = k0 + i;
            float x = (k < DU) ? u[(size_t)b * DU + k] : sC[k - DU];
            acc += x * Wq[k * QK + lane];
        }
        sPart[wave * QK + lane] = acc;
    }
    __syncthreads();
    if (t < QK) sQ[t] = bq[t] + sPart[t] + sPart[QK + t] + sPart[2 * QK + t] + sPart[3 * QK + t];
    __syncthreads();

    // qvi (threads 0..127) / qvs (threads 128..255): row dot with Q (b128 reads)
    {
        const int colh = t & 127;
        const float* Wkx = (t < 128) ? Wki : Wks;
        const float4* Wr = (const float4*)(Wkx + colh * QK);
        const float4* Qr = (const float4*)sQ;
        float acc = 0.f;
        #pragma unroll
        for (int j = 0; j < 16; ++j) acc += dot4(Wr[j], Qr[j]);
        if (t < 128) sQVi[colh] = acc;
        else qvs_w[((size_t)d * B + b) * DH + colh] = acc;
    }
    __syncthreads();

    // scores: per-row dot via 32-lane group reduction
    {
        float4 qv = ((const float4*)sQVi)[col4];
        #pragma unroll
        for (int k = 0; k < 7; ++k) {
            if (k < nrow) {
                float p = dot4(h4[k], qv);
                p = gsum32(p);
                if (col4 == 0) sSc[g + 8 * k] = p * 0.125f;
            }
        }
    }
    __syncthreads();
    if (wave == 0) {
        float s = (lane < L) ? sSc[lane] : -3.0e38f;
        float m = wmax(s);
        float e = (lane < L) ? expf(s - m) : 0.f;
        float ssum = wsum(e);
        if (lane < L) sA[lane] = e / ssum;
    }
    __syncthreads();

    // v_agg partials in registers
    {
        float4 va = make_float4(0.f, 0.f, 0.f, 0.f);
        #pragma unroll
        for (int k = 0; k < 7; ++k) {
            if (k < nrow) {
                float a = sA[g + 8 * k];
                va.x += a * h4[k].x; va.y += a * h4[k].y;
                va.z += a * h4[k].z; va.w += a * h4[k].w;
            }
        }
        sP4[t] = va;
    }
    __syncthreads();
    if (t < DH) {
        float s = 0.f;
        #pragma unroll
        for (int gg = 0; gg < 8; ++gg) s += sPf[gg * 128 + t];
        sVagg[t] = s;
    }
    __syncthreads();

    // h_i = v_agg @ Wvi + bvi, split-k 4x32
    {
        float acc = 0.f;
        const int k0 = wave * 32;
        #pragma unroll 8
        for (int i = 0; i < 32; ++i) {
            int k = k0 + i;
            acc += sVagg[k] * Wvi[k * QK + lane];
        }
        sPart[wave * QK + lane] = acc;
    }
    __syncthreads();
    if (t < QK) {
        hi_w[((size_t)d * B + b) * QK + t] =
            bvi[t] + sPart[t] + sPart[QK + t] + sPart[2 * QK + t] + sPart[3 * QK + t];
    }
}

// kstat: segment sums of h per (domain, dim). 64 blocks x 32 rows.
__global__ __launch_bounds__(256) void kstat(
    const float* __restrict__ h, const int* __restrict__ dom_ids,
    float* __restrict__ gsum, float* __restrict__ gsq, float* __restrict__ gcnt)
{
    __shared__ float sS[D * DH], sQ2[D * DH], sCnt[D];
    const int t = threadIdx.x;
    const int b0 = blockIdx.x * 32;
    for (int i = t; i < D * DH; i += 256) { sS[i] = 0.f; sQ2[i] = 0.f; }
    if (t < D) sCnt[t] = 0.f;
    __syncthreads();
    const int col = t & 127, half = t >> 7;
    for (int rr = 0; rr < 16; ++rr) {
        int b = b0 + rr * 2 + half;
        float v = h[(size_t)b * DH + col];
        int dm = dom_ids[b];
        atomicAdd(&sS[dm * DH + col], v);
        atomicAdd(&sQ2[dm * DH + col], v * v);
        if (col == 0) atomicAdd(&sCnt[dm], 1.f);
    }
    __syncthreads();
    for (int i = t; i < D * DH; i += 256) {
        atomicAdd(&gsum[i], sS[i]);
        atomicAdd(&gsq[i], sQ2[i]);
    }
    if (t < D) atomicAdd(&gcnt[t], sCnt[t]);
}

// kfin: one block per b. Shared attention (all 5 domains, Hs register-resident),
// contrastive loss, z, gb, AdaNorm epilogue (stats finalized inline).
__global__ __launch_bounds__(256, 4) void kfin(
    const float* __restrict__ h, const int* __restrict__ dom_ids,
    const float* __restrict__ Hs,     // [B,LS,DH]
    const float* __restrict__ qvs_w,  // [D,B,DH]
    const float* __restrict__ hi_w,   // [D,B,QK]
    const float* __restrict__ Wvs, const float* __restrict__ bvs,
    const float* __restrict__ Wf, const float* __restrict__ bf,
    const float* __restrict__ Wgb, const float* __restrict__ bgb,
    const float* __restrict__ gsum, const float* __restrict__ gsq,
    const float* __restrict__ gcnt,
    float* __restrict__ out, float* __restrict__ loss_out)
{
    __shared__ float4 sQV4[160];     // qvs for 5 domains [dd*32+col4]
    __shared__ float sHI[D * QK];
    __shared__ float sHS[D * QK];
    __shared__ float sS[D * 64];     // scores -> softmax weights (in place)
    __shared__ float4 sVP4[1280];    // 20 KB: vagg partials, reused for h_s partials
    __shared__ float sVA[D * DH];
    __shared__ float sInv[16];
    __shared__ float sSim[32];
    __shared__ float sZ[QK];
    __shared__ float sPartZ[256];
    __shared__ float sGB[256];

    const int b = blockIdx.x;
    const int t = threadIdx.x;
    const int lane = t & 63;
    const int wave = t >> 6;
    const int g = t >> 5;
    const int col4 = t & 31;
    const int nrow = (g < 2) ? 7 : 6;
    float* sBigF = (float*)sVP4;

    const int dm = dom_ids[b];

    // loads: Hs tile to registers + qvs + h_i to LDS
    const float* Hbase = Hs + (size_t)b * LS * DH;
    float4 h4[7];
    #pragma unroll
    for (int k = 0; k < 7; ++k) {
        if (k < nrow) h4[k] = *(const float4*)(Hbase + (g + 8 * k) * DH + 4 * col4);
    }
    if (t < 160) {
        int dd = t >> 5, c4 = t & 31;
        sQV4[t] = *(const float4*)(qvs_w + ((size_t)dd * B + b) * DH + 4 * c4);
    }
    if (t < 80) {
        int dd = t >> 4, q4 = t & 15;
        ((float4*)sHI)[t] = *(const float4*)(hi_w + ((size_t)dd * B + b) * QK + 4 * q4);
    }
    __syncthreads();

    // scores for all 5 domains
    #pragma unroll
    for (int dd = 0; dd < D; ++dd) {
        float4 qv = sQV4[dd * 32 + col4];
        #pragma unroll
        for (int k = 0; k < 7; ++k) {
            if (k < nrow) {
                float p = dot4(h4[k], qv);
                p = gsum32(p);
                if (col4 == 0) sS[dd * 64 + g + 8 * k] = p * 0.125f;
            }
        }
    }
    __syncthreads();
    // 5 softmaxes over waves
    for (int dd = wave; dd < D; dd += 4) {
        float s = (lane < LS) ? sS[dd * 64 + lane] : -3.0e38f;
        float m = wmax(s);
        float e = (lane < LS) ? expf(s - m) : 0.f;
        float ssum = wsum(e);
        if (lane < LS) sS[dd * 64 + lane] = e / ssum;
    }
    __syncthreads();

    // v_agg partials for all domains (registers)
    {
        float4 va[D];
        #pragma unroll
        for (int dd = 0; dd < D; ++dd) va[dd] = make_float4(0.f, 0.f, 0.f, 0.f);
        #pragma unroll
        for (int k = 0; k < 7; ++k) {
            if (k < nrow) {
                float4 hv = h4[k];
                #pragma unroll
                for (int dd = 0; dd < D; ++dd) {
                    float a = sS[dd * 64 + g + 8 * k];
                    va[dd].x += a * hv.x; va[dd].y += a * hv.y;
                    va[dd].z += a * hv.z; va[dd].w += a * hv.w;
                }
            }
        }
        #pragma unroll
        for (int dd = 0; dd < D; ++dd) sVP4[dd * 256 + t] = va[dd];
    }
    __syncthreads();
    // combine: vagg[dd,col]
    for (int o = t; o < D * DH; o += 256) {
        int dd = o >> 7, col = o & 127;
        float s = 0.f;
        #pragma unroll
        for (int gg = 0; gg < 8; ++gg) s += sBigF[dd * 1024 + gg * 128 + col];
        sVA[o] = s;
    }
    __syncthreads();

    // h_s = vagg @ Wvs + bvs: 320 outputs, split-k 4 -> 1280 partial tasks
    #pragma unroll
    for (int j = 0; j < 5; ++j) {
        int tau = t + j * 256;
        int kq = tau / 320;
        int o = tau - kq * 320;
        int dd = o >> 6, q = o & 63;
        float acc = 0.f;
        const int k0 = kq * 32;
        #pragma unroll 8
        for (int i = 0; i < 32; ++i) {
            int k = k0 + i;
            acc += sVA[dd * 128 + k] * Wvs[k * QK + q];
        }
        sBigF[tau] = acc;
    }
    __syncthreads();
    for (int o = t; o < D * QK; o += 256) {
        int q = o & 63;
        sHS[o] = bvs[q] + sBigF[o] + sBigF[o + 320] + sBigF[o + 640] + sBigF[o + 960];
    }
    __syncthreads();

    // contrastive loss: inverse norms
    for (int v = wave; v < 2 * D; v += 4) {
        float x = (v < D) ? sHI[v * QK + lane] : sHS[(v - D) * QK + lane];
        float ss = wsum(x * x);
        if (lane == 0) sInv[v] = 1.0f / fmaxf(sqrtf(ss), 1e-12f);
    }
    __syncthreads();
    // 25 all-sim dots + 5 pos dots
    for (int p = wave; p < 30; p += 4) {
        float s;
        if (p < 25) {
            int dd = p / 5, e = p - dd * 5;
            s = wsum(sHI[dd * QK + lane] * sHI[e * QK + lane] * sInv[dd] * sInv[e]);
        } else {
            int dd = p - 25;
            s = wsum(sHI[dd * QK + lane] * sHS[dd * QK + lane] * sInv[dd] * sInv[D + dd]);
        }
        if (lane == 0) sSim[p] = s;
    }
    __syncthreads();
    if (t == 0) {
        float tot = 0.f;
        #pragma unroll
        for (int dd = 0; dd < D; ++dd) {
            float den = 0.f;
            #pragma unroll
            for (int e = 0; e < D; ++e) den += expf(sSim[dd * 5 + e]);
            tot += logf(expf(sSim[25 + dd]) / (den + 1e-8f) + 1e-8f);
        }
        atomicAdd(loss_out, -tot / (float)(B * D));
    }

    // z = [h_i[dm], h_s[dm]] @ Wf + bf, split-k 4x32
    {
        const int kq = wave, q = lane;
        float acc = 0.f;
        const int k0 = kq * 32;
        #pragma unroll 8
        for (int i = 0; i < 32; ++i) {
            int k = k0 + i;
            float x = (k < QK) ? sHI[dm * QK + k] : sHS[dm * QK + (k - QK)];
            acc += x * Wf[k * CD + q];
        }
        sPartZ[t] = acc;
    }
    __syncthreads();
    if (t < QK) sZ[t] = bf[t] + sPartZ[t] + sPartZ[64 + t] + sPartZ[128 + t] + sPartZ[192 + t];
    __syncthreads();

    // gb = z @ Wgb + bgb (256 outputs, one per thread)
    {
        float acc = bgb[t];
        #pragma unroll 8
        for (int k = 0; k < CD; ++k) acc += sZ[k] * Wgb[k * (2 * DH) + t];
        sGB[t] = acc;
    }
    __syncthreads();

    // AdaNorm epilogue with inline stat finalize
    if (t < DH) {
        float c = fmaxf(gcnt[dm], 1.0f);
        float mu = gsum[dm * DH + t] / c;
        float va = gsq[dm * DH + t] / c - mu * mu;
        float hv = h[(size_t)b * DH + t];
        float hn = (hv - mu) / sqrtf(va + EPS);
        out[(size_t)b * DH + t] = sGB[t] * hn + sGB[DH + t] + hv;
    }
}

extern "C" void kernel_launch(void* const* d_in, const int* in_sizes, int n_in,
                              void* d_out, int out_size, void* d_ws, size_t ws_size,
                              hipStream_t stream)
{
    (void)in_sizes; (void)n_in; (void)out_size; (void)ws_size;
    const float* u   = (const float*)d_in[0];
    const float* Hi  = (const float*)d_in[1];
    const float* Hs  = (const float*)d_in[2];
    const float* h   = (const float*)d_in[3];
    const int*   dom = (const int*)d_in[4];
    const float* Wq  = (const float*)d_in[5];
    const float* bq  = (const float*)d_in[6];
    const float* Wki = (const float*)d_in[7];
    // d_in[8] = bki: unused (softmax shift-invariance)
    const float* Wvi = (const float*)d_in[9];
    const float* bvi = (const float*)d_in[10];
    const float* Wks = (const float*)d_in[11];
    // d_in[12] = bks: unused (softmax shift-invariance)
    const float* Wvs = (const float*)d_in[13];
    const float* bvs = (const float*)d_in[14];
    const float* Wf  = (const float*)d_in[15];
    const float* bf  = (const float*)d_in[16];
    const float* Wgb = (const float*)d_in[17];
    const float* bgb = (const float*)d_in[18];

    float* out = (float*)d_out;
    float* loss_out = out + (size_t)B * DH;

    float* ws = (float*)d_ws;
    float* qvs_w = ws;                               // D*B*DH
    float* hi_w  = qvs_w + (size_t)D * B * DH;       // D*B*QK
    float* gsum  = hi_w + (size_t)D * B * QK;        // D*DH
    float* gsq   = gsum + D * DH;                    // D*DH
    float* gcnt  = gsq + D * DH;                     // 8

    hipMemsetAsync(gsum, 0, (size_t)(2 * D * DH + 8) * sizeof(float), stream);
    hipMemsetAsync(loss_out, 0, sizeof(float), stream);

    hipLaunchKernelGGL(kstat, dim3(B / 32), dim3(256), 0, stream, h, dom, gsum, gsq, gcnt);
    hipLaunchKernelGGL(kin, dim3(B, D), dim3(256), 0, stream,
                       u, Hi, Wq, bq, Wki, Wvi, bvi, Wks, qvs_w, hi_w);
    hipLaunchKernelGGL(kfin, dim3(B), dim3(256), 0, stream,
                       h, dom, Hs, qvs_w, hi_w, Wvs, bvs, Wf, bf, Wgb, bgb,
                       gsum, gsq, gcnt, out, loss_out);
}

// Round 4
// 560.051 us; speedup vs baseline: 3.5359x; 1.0941x over previous
//
#include <hip/hip_runtime.h>
#include <math.h>

#define D 5
#define B 2048
#define L 50
#define LS 50
#define DH 128
#define DU 128
#define QK 64
#define CD 64
#define EPS 1e-5f

__device__ __forceinline__ float wsum(float v) {
    v += __shfl_xor(v, 1, 64);
    v += __shfl_xor(v, 2, 64);
    v += __shfl_xor(v, 4, 64);
    v += __shfl_xor(v, 8, 64);
    v += __shfl_xor(v, 16, 64);
    v += __shfl_xor(v, 32, 64);
    return v;
}

__device__ __forceinline__ float wmax(float v) {
    v = fmaxf(v, __shfl_xor(v, 1, 64));
    v = fmaxf(v, __shfl_xor(v, 2, 64));
    v = fmaxf(v, __shfl_xor(v, 4, 64));
    v = fmaxf(v, __shfl_xor(v, 8, 64));
    v = fmaxf(v, __shfl_xor(v, 16, 64));
    v = fmaxf(v, __shfl_xor(v, 32, 64));
    return v;
}

// reduction across a 32-lane group (xor bits 0..4 keep bit5 invariant)
__device__ __forceinline__ float gsum32(float v) {
    v += __shfl_xor(v, 1, 64);
    v += __shfl_xor(v, 2, 64);
    v += __shfl_xor(v, 4, 64);
    v += __shfl_xor(v, 8, 64);
    v += __shfl_xor(v, 16, 64);
    return v;
}

__device__ __forceinline__ float dot4(float4 a, float4 b) {
    return a.x * b.x + a.y * b.y + a.z * b.z + a.w * b.w;
}

// ksetup: blocks 0..127 compute G matrices (j-major, coalesced-consumable):
//   Gi[j*DH+k] = sum_q Wq[(DU+j),q] * Wki[k,q];  Gs likewise with Wks.
// blocks 128.. compute per-b u-part of qv (bq folded here):
//   qu_i[b,k] = sum_q Wki[k,q] * (u[b]@Wq_u + bq)[q];  qu_s likewise.
__global__ __launch_bounds__(256) void ksetup(
    const float* __restrict__ u,
    const float* __restrict__ Wq, const float* __restrict__ bq,
    const float* __restrict__ Wki, const float* __restrict__ Wks,
    float* __restrict__ Gi, float* __restrict__ Gs,
    float* __restrict__ qu_i, float* __restrict__ qu_s)
{
    const int t = threadIdx.x;
    if (blockIdx.x < DH) {
        __shared__ float sWqc[QK];
        const int j = blockIdx.x;
        if (t < QK) sWqc[t] = Wq[(DU + j) * QK + t];
        __syncthreads();
        const int k = t & 127;
        const float* Wk = (t < 128) ? Wki : Wks;
        const float4* Wr = (const float4*)(Wk + k * QK);
        const float4* cq = (const float4*)sWqc;
        float acc = 0.f;
        #pragma unroll
        for (int q4 = 0; q4 < 16; ++q4) acc += dot4(Wr[q4], cq[q4]);
        if (t < 128) Gi[j * DH + k] = acc;
        else Gs[j * DH + k] = acc;
    } else {
        __shared__ float sPart[4 * QK];
        __shared__ float sQu[QK];
        const int b = blockIdx.x - DH;
        const int lane = t & 63, wave = t >> 6;
        float acc = 0.f;
        const int k0 = wave * 32;
        #pragma unroll 8
        for (int i = 0; i < 32; ++i) {
            int k = k0 + i;
            acc += u[(size_t)b * DU + k] * Wq[k * QK + lane];
        }
        sPart[wave * QK + lane] = acc;
        __syncthreads();
        if (t < QK) sQu[t] = bq[t] + sPart[t] + sPart[64 + t] + sPart[128 + t] + sPart[192 + t];
        __syncthreads();
        const int k = t & 127;
        const float* Wk = (t < 128) ? Wki : Wks;
        const float4* Wr = (const float4*)(Wk + k * QK);
        const float4* cq = (const float4*)sQu;
        float acc2 = 0.f;
        #pragma unroll
        for (int q4 = 0; q4 < 16; ++q4) acc2 += dot4(Wr[q4], cq[q4]);
        if (t < 128) qu_i[(size_t)b * DH + k] = acc2;
        else qu_s[(size_t)b * DH + k] = acc2;
    }
}

// kin: one block per (2 b's, d). H register-resident.
// Thread layout: bb = t>>7 (which b), gg = (t&127)>>5 (row group), col4 = t&31.
// Thread owns rows r = gg + 4k (k < nr), cols 4*col4..4*col4+3 of H[b0+bb].
__global__ __launch_bounds__(256, 4) void kin(
    const float* __restrict__ Hi,   // [D,B,L,DH]
    const float* __restrict__ Gi, const float* __restrict__ Gs,
    const float* __restrict__ qu_i, const float* __restrict__ qu_s,
    const float* __restrict__ Wvi, const float* __restrict__ bvi,
    float* __restrict__ qvs_w,      // [D,B,DH]
    float* __restrict__ hi_w)       // [D,B,QK]
{
    __shared__ float4 sP4[256];      // partials: c, then vagg
    __shared__ float sC2[2 * DH];    // c interleaved [j][bb]
    __shared__ float sQVi[2 * DH];   // qv_i [bb][k]
    __shared__ float sSc[128];
    __shared__ float sA[128];
    __shared__ float sVagg[2 * DH];  // [bb][col]
    __shared__ float sPA[256], sPB[256];

    const int b0 = blockIdx.x * 2;
    const int d = blockIdx.y;
    const int t = threadIdx.x;
    const int lane = t & 63, wave = t >> 6;
    const int bb = t >> 7;
    const int tb = t & 127;
    const int gg = tb >> 5;
    const int col4 = t & 31;
    const int nr = (gg < 2) ? 13 : 12;
    const float* sPf = (const float*)sP4;

    // H tile -> registers (coalesced b128)
    const float* Hbase = Hi + ((size_t)d * B + (b0 + bb)) * (L * DH);
    float4 h4[13];
    #pragma unroll
    for (int k = 0; k < 13; ++k)
        if (k < nr) h4[k] = *(const float4*)(Hbase + (gg + 4 * k) * DH + 4 * col4);

    // c partials
    {
        float4 cs = make_float4(0.f, 0.f, 0.f, 0.f);
        #pragma unroll
        for (int k = 0; k < 13; ++k)
            if (k < nr) { cs.x += h4[k].x; cs.y += h4[k].y; cs.z += h4[k].z; cs.w += h4[k].w; }
        sP4[t] = cs;
    }
    __syncthreads();
    {
        const int bbc = t >> 7, col = t & 127;
        float s = sPf[bbc * 512 + col] + sPf[bbc * 512 + 128 + col]
                + sPf[bbc * 512 + 256 + col] + sPf[bbc * 512 + 384 + col];
        sC2[col * 2 + bbc] = s * (1.0f / (float)L);
    }
    __syncthreads();

    // qv = qu + G^T c for both b's; coalesced dword G reads, LDS float2 c broadcast
    {
        const int mat = t >> 7, k = t & 127;
        const float* G = mat ? Gs : Gi;
        const float* qum = mat ? qu_s : qu_i;
        float a0 = qum[(size_t)b0 * DH + k];
        float a1 = qum[(size_t)(b0 + 1) * DH + k];
        const float2* c2 = (const float2*)sC2;
        #pragma unroll 8
        for (int j = 0; j < DH; ++j) {
            float g = G[j * DH + k];
            float2 c = c2[j];
            a0 += c.x * g;
            a1 += c.y * g;
        }
        if (mat == 0) { sQVi[k] = a0; sQVi[DH + k] = a1; }
        else {
            qvs_w[((size_t)d * B + b0) * DH + k] = a0;
            qvs_w[((size_t)d * B + b0 + 1) * DH + k] = a1;
        }
    }
    __syncthreads();

    // scores
    {
        float4 qv = ((const float4*)sQVi)[bb * 32 + col4];
        #pragma unroll
        for (int k = 0; k < 13; ++k)
            if (k < nr) {
                float p = dot4(h4[k], qv);
                p = gsum32(p);
                if (col4 == 0) sSc[bb * 64 + gg + 4 * k] = p * 0.125f;
            }
    }
    __syncthreads();
    if (wave < 2) {
        float s = (lane < L) ? sSc[wave * 64 + lane] : -3.0e38f;
        float m = wmax(s);
        float e = (lane < L) ? expf(s - m) : 0.f;
        float ssum = wsum(e);
        if (lane < L) sA[wave * 64 + lane] = e / ssum;
    }
    __syncthreads();

    // vagg partials
    {
        float4 va = make_float4(0.f, 0.f, 0.f, 0.f);
        #pragma unroll
        for (int k = 0; k < 13; ++k)
            if (k < nr) {
                float a = sA[bb * 64 + gg + 4 * k];
                va.x += a * h4[k].x; va.y += a * h4[k].y;
                va.z += a * h4[k].z; va.w += a * h4[k].w;
            }
        sP4[t] = va;
    }
    __syncthreads();
    {
        const int bbc = t >> 7, col = t & 127;
        sVagg[bbc * 128 + col] = sPf[bbc * 512 + col] + sPf[bbc * 512 + 128 + col]
                               + sPf[bbc * 512 + 256 + col] + sPf[bbc * 512 + 384 + col];
    }
    __syncthreads();

    // h_i = vagg @ Wvi + bvi for both b's (Wvi loads shared)
    {
        const int q = t & 63, kq = t >> 6;
        const int k0 = kq * 32;
        float a0 = 0.f, a1 = 0.f;
        #pragma unroll 8
        for (int i = 0; i < 32; ++i) {
            int k = k0 + i;
            float w = Wvi[k * QK + q];
            a0 += sVagg[k] * w;
            a1 += sVagg[128 + k] * w;
        }
        sPA[kq * 64 + q] = a0;
        sPB[kq * 64 + q] = a1;
    }
    __syncthreads();
    if (t < 128) {
        const int bw = t >> 6, q = t & 63;
        const float* P = bw ? sPB : sPA;
        hi_w[((size_t)d * B + b0 + bw) * QK + q] =
            bvi[q] + P[q] + P[64 + q] + P[128 + q] + P[192 + q];
    }
}

// kstat: segment sums of h per (domain, dim). 64 blocks x 32 rows.
__global__ __launch_bounds__(256) void kstat(
    const float* __restrict__ h, const int* __restrict__ dom_ids,
    float* __restrict__ gsum, float* __restrict__ gsq, float* __restrict__ gcnt)
{
    __shared__ float sS[D * DH], sQ2[D * DH], sCnt[D];
    const int t = threadIdx.x;
    const int b0 = blockIdx.x * 32;
    for (int i = t; i < D * DH; i += 256) { sS[i] = 0.f; sQ2[i] = 0.f; }
    if (t < D) sCnt[t] = 0.f;
    __syncthreads();
    const int col = t & 127, half = t >> 7;
    for (int rr = 0; rr < 16; ++rr) {
        int b = b0 + rr * 2 + half;
        float v = h[(size_t)b * DH + col];
        int dm = dom_ids[b];
        atomicAdd(&sS[dm * DH + col], v);
        atomicAdd(&sQ2[dm * DH + col], v * v);
        if (col == 0) atomicAdd(&sCnt[dm], 1.f);
    }
    __syncthreads();
    for (int i = t; i < D * DH; i += 256) {
        atomicAdd(&gsum[i], sS[i]);
        atomicAdd(&gsq[i], sQ2[i]);
    }
    if (t < D) atomicAdd(&gcnt[t], sCnt[t]);
}

// ksh: one block per b. Shared attention for all 5 domains, Hs register-resident.
__global__ __launch_bounds__(256, 4) void ksh(
    const float* __restrict__ Hs,     // [B,LS,DH]
    const float* __restrict__ qvs_w,  // [D,B,DH]
    const float* __restrict__ Wvs, const float* __restrict__ bvs,
    float* __restrict__ hs_w)         // [D,B,QK]
{
    __shared__ float4 sQV4[160];
    __shared__ float sS[D * 64];
    __shared__ float4 sVP4[1280];    // 20 KB: vagg partials / h_s partials
    __shared__ float sVA[D * DH];

    const int b = blockIdx.x;
    const int t = threadIdx.x;
    const int lane = t & 63;
    const int wave = t >> 6;
    const int g = t >> 5;
    const int col4 = t & 31;
    const int nrow = (g < 2) ? 7 : 6;
    float* sBigF = (float*)sVP4;

    const float* Hbase = Hs + (size_t)b * LS * DH;
    float4 h4[7];
    #pragma unroll
    for (int k = 0; k < 7; ++k)
        if (k < nrow) h4[k] = *(const float4*)(Hbase + (g + 8 * k) * DH + 4 * col4);
    if (t < 160) {
        int dd = t >> 5, c4 = t & 31;
        sQV4[t] = *(const float4*)(qvs_w + ((size_t)dd * B + b) * DH + 4 * c4);
    }
    __syncthreads();

    #pragma unroll
    for (int dd = 0; dd < D; ++dd) {
        float4 qv = sQV4[dd * 32 + col4];
        #pragma unroll
        for (int k = 0; k < 7; ++k)
            if (k < nrow) {
                float p = dot4(h4[k], qv);
                p = gsum32(p);
                if (col4 == 0) sS[dd * 64 + g + 8 * k] = p * 0.125f;
            }
    }
    __syncthreads();
    for (int dd = wave; dd < D; dd += 4) {
        float s = (lane < LS) ? sS[dd * 64 + lane] : -3.0e38f;
        float m = wmax(s);
        float e = (lane < LS) ? expf(s - m) : 0.f;
        float ssum = wsum(e);
        if (lane < LS) sS[dd * 64 + lane] = e / ssum;
    }
    __syncthreads();

    {
        float4 va[D];
        #pragma unroll
        for (int dd = 0; dd < D; ++dd) va[dd] = make_float4(0.f, 0.f, 0.f, 0.f);
        #pragma unroll
        for (int k = 0; k < 7; ++k)
            if (k < nrow) {
                float4 hv = h4[k];
                #pragma unroll
                for (int dd = 0; dd < D; ++dd) {
                    float a = sS[dd * 64 + g + 8 * k];
                    va[dd].x += a * hv.x; va[dd].y += a * hv.y;
                    va[dd].z += a * hv.z; va[dd].w += a * hv.w;
                }
            }
        #pragma unroll
        for (int dd = 0; dd < D; ++dd) sVP4[dd * 256 + t] = va[dd];
    }
    __syncthreads();
    for (int o = t; o < D * DH; o += 256) {
        int dd = o >> 7, col = o & 127;
        float s = 0.f;
        #pragma unroll
        for (int gg = 0; gg < 8; ++gg) s += sBigF[dd * 1024 + gg * 128 + col];
        sVA[o] = s;
    }
    __syncthreads();

    // h_s = vagg @ Wvs + bvs: 320 outputs x split-k 4 (Wvs amortized over 5 d)
    #pragma unroll
    for (int j = 0; j < 5; ++j) {
        int tau = t + j * 256;
        int kq = tau / 320;
        int o = tau - kq * 320;
        int dd = o >> 6, q = o & 63;
        float acc = 0.f;
        const int k0 = kq * 32;
        #pragma unroll 8
        for (int i = 0; i < 32; ++i) {
            int k = k0 + i;
            acc += sVA[dd * 128 + k] * Wvs[k * QK + q];
        }
        sBigF[tau] = acc;
    }
    __syncthreads();
    for (int o = t; o < D * QK; o += 256) {
        int dd = o >> 6, q = o & 63;
        hs_w[((size_t)dd * B + b) * QK + q] =
            bvs[q] + sBigF[o] + sBigF[o + 320] + sBigF[o + 640] + sBigF[o + 960];
    }
}

// kfin: one block per b. Loss, z, gb, AdaNorm epilogue.
__global__ __launch_bounds__(256) void kfin(
    const float* __restrict__ h, const int* __restrict__ dom_ids,
    const float* __restrict__ hi_w, const float* __restrict__ hs_w,
    const float* __restrict__ Wf, const float* __restrict__ bf,
    const float* __restrict__ Wgb, const float* __restrict__ bgb,
    const float* __restrict__ gsum, const float* __restrict__ gsq,
    const float* __restrict__ gcnt,
    float* __restrict__ out, float* __restrict__ loss_out)
{
    __shared__ float sHI[D * QK], sHS[D * QK];
    __shared__ float sInv[16], sSim[32], sZ[QK], sPartZ[256], sGB[256];

    const int b = blockIdx.x;
    const int t = threadIdx.x;
    const int lane = t & 63;
    const int wave = t >> 6;
    const int dm = dom_ids[b];

    if (t < 80) {
        int dd = t >> 4, q4 = t & 15;
        ((float4*)sHI)[t] = *(const float4*)(hi_w + ((size_t)dd * B + b) * QK + 4 * q4);
        ((float4*)sHS)[t] = *(const float4*)(hs_w + ((size_t)dd * B + b) * QK + 4 * q4);
    }
    __syncthreads();

    for (int v = wave; v < 2 * D; v += 4) {
        float x = (v < D) ? sHI[v * QK + lane] : sHS[(v - D) * QK + lane];
        float ss = wsum(x * x);
        if (lane == 0) sInv[v] = 1.0f / fmaxf(sqrtf(ss), 1e-12f);
    }
    __syncthreads();
    for (int p = wave; p < 30; p += 4) {
        float s;
        if (p < 25) {
            int dd = p / 5, e = p - dd * 5;
            s = wsum(sHI[dd * QK + lane] * sHI[e * QK + lane] * sInv[dd] * sInv[e]);
        } else {
            int dd = p - 25;
            s = wsum(sHI[dd * QK + lane] * sHS[dd * QK + lane] * sInv[dd] * sInv[D + dd]);
        }
        if (lane == 0) sSim[p] = s;
    }
    __syncthreads();
    if (t == 0) {
        float tot = 0.f;
        #pragma unroll
        for (int dd = 0; dd < D; ++dd) {
            float den = 0.f;
            #pragma unroll
            for (int e = 0; e < D; ++e) den += expf(sSim[dd * 5 + e]);
            tot += logf(expf(sSim[25 + dd]) / (den + 1e-8f) + 1e-8f);
        }
        atomicAdd(loss_out, -tot / (float)(B * D));
    }

    // z = [h_i[dm], h_s[dm]] @ Wf + bf
    {
        const int kq = wave, q = lane;
        float acc = 0.f;
        const int k0 = kq * 32;
        #pragma unroll 8
        for (int i = 0; i < 32; ++i) {
            int k = k0 + i;
            float x = (k < QK) ? sHI[dm * QK + k] : sHS[dm * QK + (k - QK)];
            acc += x * Wf[k * CD + q];
        }
        sPartZ[t] = acc;
    }
    __syncthreads();
    if (t < QK) sZ[t] = bf[t] + sPartZ[t] + sPartZ[64 + t] + sPartZ[128 + t] + sPartZ[192 + t];
    __syncthreads();

    {
        float acc = bgb[t];
        #pragma unroll 8
        for (int k = 0; k < CD; ++k) acc += sZ[k] * Wgb[k * (2 * DH) + t];
        sGB[t] = acc;
    }
    __syncthreads();

    if (t < DH) {
        float c = fmaxf(gcnt[dm], 1.0f);
        float mu = gsum[dm * DH + t] / c;
        float va = gsq[dm * DH + t] / c - mu * mu;
        float hv = h[(size_t)b * DH + t];
        float hn = (hv - mu) / sqrtf(va + EPS);
        out[(size_t)b * DH + t] = sGB[t] * hn + sGB[DH + t] + hv;
    }
}

extern "C" void kernel_launch(void* const* d_in, const int* in_sizes, int n_in,
                              void* d_out, int out_size, void* d_ws, size_t ws_size,
                              hipStream_t stream)
{
    (void)in_sizes; (void)n_in; (void)out_size; (void)ws_size;
    const float* u   = (const float*)d_in[0];
    const float* Hi  = (const float*)d_in[1];
    const float* Hs  = (const float*)d_in[2];
    const float* h   = (const float*)d_in[3];
    const int*   dom = (const int*)d_in[4];
    const float* Wq  = (const float*)d_in[5];
    const float* bq  = (const float*)d_in[6];
    const float* Wki = (const float*)d_in[7];
    // d_in[8] = bki: unused (softmax shift-invariance)
    const float* Wvi = (const float*)d_in[9];
    const float* bvi = (const float*)d_in[10];
    const float* Wks = (const float*)d_in[11];
    // d_in[12] = bks: unused (softmax shift-invariance)
    const float* Wvs = (const float*)d_in[13];
    const float* bvs = (const float*)d_in[14];
    const float* Wf  = (const float*)d_in[15];
    const float* bf  = (const float*)d_in[16];
    const float* Wgb = (const float*)d_in[17];
    const float* bgb = (const float*)d_in[18];

    float* out = (float*)d_out;
    float* loss_out = out + (size_t)B * DH;

    float* ws = (float*)d_ws;
    float* Gi    = ws;                                // DH*DH
    float* Gs    = Gi + DH * DH;                      // DH*DH
    float* qu_i  = Gs + DH * DH;                      // B*DH
    float* qu_s  = qu_i + (size_t)B * DH;             // B*DH
    float* qvs_w = qu_s + (size_t)B * DH;             // D*B*DH
    float* hi_w  = qvs_w + (size_t)D * B * DH;        // D*B*QK
    float* hs_w  = hi_w + (size_t)D * B * QK;         // D*B*QK
    float* gsum  = hs_w + (size_t)D * B * QK;         // D*DH
    float* gsq   = gsum + D * DH;                     // D*DH
    float* gcnt  = gsq + D * DH;                      // 8

    hipMemsetAsync(gsum, 0, (size_t)(2 * D * DH + 8) * sizeof(float), stream);
    hipMemsetAsync(loss_out, 0, sizeof(float), stream);

    hipLaunchKernelGGL(ksetup, dim3(DH + B), dim3(256), 0, stream,
                       u, Wq, bq, Wki, Wks, Gi, Gs, qu_i, qu_s);
    hipLaunchKernelGGL(kstat, dim3(B / 32), dim3(256), 0, stream, h, dom, gsum, gsq, gcnt);
    hipLaunchKernelGGL(kin, dim3(B / 2, D), dim3(256), 0, stream,
                       Hi, Gi, Gs, qu_i, qu_s, Wvi, bvi, qvs_w, hi_w);
    hipLaunchKernelGGL(ksh, dim3(B), dim3(256), 0, stream, Hs, qvs_w, Wvs, bvs, hs_w);
    hipLaunchKernelGGL(kfin, dim3(B), dim3(256), 0, stream,
                       h, dom, hi_w, hs_w, Wf, bf, Wgb, bgb, gsum, gsq, gcnt, out, loss_out);
}